// Round 7
// baseline (195.549 us; speedup 1.0000x reference)
//
#include <hip/hip_runtime.h>

#define BB 16384
#define LL 200
#define DD 100
#define VV 100000

// INSTRUMENTATION ROUND: each kernel repeats its own work REP times with a
// rotated (bijective, mod-N shifted) work assignment so (a) every rep issues
// real memory traffic at different addresses (no hoisting), (b) every output
// element is written the same value each rep (deterministic, race-benign),
// (c) each kernel's dispatch duration exceeds the ~40us harness fills and
// becomes visible in the rocprof top-5 WITH its counters.
#define REP1 16   // rowdot: 15*6250 = 93750 < VV -> single conditional subtract
#define REP2 8    // pool:    7*2048 = 14336 < BB

// Kernel 1 (R3-proven shape): rowdot[v] = sum_d E[v,d]*w[d].
// Half-wave (32 lanes) per row, lanes 0..24 load one float4 (25 x 16B = row).
__global__ __launch_bounds__(256) void rowdot_kernel(const float4* __restrict__ E4,
                                                     const float4* __restrict__ w4,
                                                     float* __restrict__ rowdot) {
    const int tid  = blockIdx.x * blockDim.x + threadIdx.x;
    const int wave = tid >> 6;
    const int lane = threadIdx.x & 63;
    const int half = lane >> 5;
    const int sub  = lane & 31;

    float4 wv = make_float4(0.f, 0.f, 0.f, 0.f);
    if (sub < 25) wv = w4[sub];

    const int r0 = wave * 2 + half;      // 0..99999
    #pragma unroll 1
    for (int rep = 0; rep < REP1; ++rep) {
        int r = r0 + rep * 6250;         // bijective shift mod VV
        if (r >= VV) r -= VV;
        float s = 0.0f;
        if (sub < 25) {
            float4 v = E4[(size_t)r * 25 + sub];
            s = v.x * wv.x + v.y * wv.y + v.z * wv.z + v.w * wv.w;
        }
        #pragma unroll
        for (int off = 16; off > 0; off >>= 1)
            s += __shfl_xor(s, off, 64);
        if (sub == 0) rowdot[r] = s;     // same value every rep
    }
}

// Kernel 2 (R3-proven shape): out[b] = (1/L) * sum_l rowdot[idx[b,l]].
// One wave per batch row; lanes 0..49 load one int4 (50 x int4 = 200 idx).
__global__ __launch_bounds__(256) void pool_kernel(const int4* __restrict__ idx4,
                                                   const float* __restrict__ rowdot,
                                                   float* __restrict__ out) {
    const int tid  = blockIdx.x * blockDim.x + threadIdx.x;
    const int wave = tid >> 6;
    const int lane = threadIdx.x & 63;

    #pragma unroll 1
    for (int rep = 0; rep < REP2; ++rep) {
        int b = wave + rep * 2048;       // bijective shift mod BB
        if (b >= BB) b -= BB;
        float s = 0.0f;
        if (lane < 50) {
            int4 i4 = idx4[(size_t)b * 50 + lane];
            float g0 = rowdot[i4.x], g1 = rowdot[i4.y];
            float g2 = rowdot[i4.z], g3 = rowdot[i4.w];
            s = (g0 + g1) + (g2 + g3);
        }
        #pragma unroll
        for (int off = 32; off > 0; off >>= 1)
            s += __shfl_xor(s, off, 64);
        if (lane == 0) out[b] = s * (1.0f / LL);  // same value every rep
    }
}

extern "C" void kernel_launch(void* const* d_in, const int* in_sizes, int n_in,
                              void* d_out, int out_size, void* d_ws, size_t ws_size,
                              hipStream_t stream) {
    const int4*   idx4   = (const int4*)d_in[0];      // [B, L] int32 as int4
    const float4* E4     = (const float4*)d_in[1];    // [V, D] f32 as float4
    const float4* w4     = (const float4*)d_in[2];    // [D, 1] f32 as float4
    float*        out    = (float*)d_out;             // [B, 1] f32
    float*        rowdot = (float*)d_ws;              // 400 KB scratch

    // Same grids as the 28.6us R3 config.
    rowdot_kernel<<<VV / 8, 256, 0, stream>>>(E4, w4, rowdot);   // 12500 blocks
    pool_kernel<<<BB / 4, 256, 0, stream>>>(idx4, rowdot, out);  // 4096 blocks
}

// Round 8
// 28.490 us; speedup vs baseline: 6.8637x; 6.8637x over previous
//
#include <hip/hip_runtime.h>

#define BB 16384
#define LL 200
#define DD 100
#define VV 100000
#define CHUNK 33336              // 3 chunks cover 100000; 133,344 B LDS
#define NCHUNK 3

// Kernel 1 (R3-proven, ~5.6us): rowdot[v] = sum_d E[v,d]*w[d].
// Half-wave (32 lanes) per row, lanes 0..24 load one float4 (25 x 16B = row).
__global__ __launch_bounds__(256) void rowdot_kernel(const float4* __restrict__ E4,
                                                     const float4* __restrict__ w4,
                                                     float* __restrict__ rowdot) {
    const int tid  = blockIdx.x * blockDim.x + threadIdx.x;
    const int wave = tid >> 6;
    const int lane = threadIdx.x & 63;
    const int half = lane >> 5;
    const int sub  = lane & 31;

    float4 wv = make_float4(0.f, 0.f, 0.f, 0.f);
    if (sub < 25) wv = w4[sub];

    const int r = wave * 2 + half;
    float s = 0.0f;
    if (sub < 25) {
        float4 v = E4[(size_t)r * 25 + sub];
        s = v.x * wv.x + v.y * wv.y + v.z * wv.z + v.w * wv.w;
    }
    #pragma unroll
    for (int off = 16; off > 0; off >>= 1)
        s += __shfl_xor(s, off, 64);
    if (sub == 0) rowdot[r] = s;
}

// Kernel 2: LDS-staged gather. 256 blocks x 1024 threads; block owns 64 rows,
// wave owns 4 rows, lanes 0..49 hold each row's 200 indices as int4 in regs.
// 3 passes: stage 133KB of rowdot into LDS (coalesced), barrier, predicated
// in-range accumulate from LDS (no TA involvement), barrier.
__global__ __launch_bounds__(1024) void pool_kernel(const int4* __restrict__ idx4,
                                                    const float* __restrict__ rowdot,
                                                    float* __restrict__ out) {
    __shared__ float sh[CHUNK];
    const int t    = threadIdx.x;
    const int wave = t >> 6;          // 0..15
    const int lane = t & 63;
    const int row0 = blockIdx.x * 64 + wave * 4;
    const bool act = lane < 50;

    // preload indices: 4 rows x (50 lanes x int4) — read once, held in regs
    int4 pf[4];
    #pragma unroll
    for (int r = 0; r < 4; ++r)
        pf[r] = act ? idx4[(size_t)(row0 + r) * 50 + lane]
                    : make_int4(0, 0, 0, 0);

    float acc[4] = {0.f, 0.f, 0.f, 0.f};

    #pragma unroll 1
    for (int c = 0; c < NCHUNK; ++c) {
        const int base = c * CHUNK;
        __syncthreads();   // previous chunk's readers done before overwrite
        // stage CHUNK floats = 8334 float4, 1024 threads -> 9 masked iters
        #pragma unroll 1
        for (int k = t; k < CHUNK / 4; k += 1024)
            ((float4*)sh)[k] = ((const float4*)rowdot)[base / 4 + k];
        __syncthreads();
        if (act) {
            #pragma unroll
            for (int r = 0; r < 4; ++r) {
                int4 i4 = pf[r];
                int a0 = i4.x - base, a1 = i4.y - base;
                int a2 = i4.z - base, a3 = i4.w - base;
                if ((unsigned)a0 < (unsigned)CHUNK) acc[r] += sh[a0];
                if ((unsigned)a1 < (unsigned)CHUNK) acc[r] += sh[a1];
                if ((unsigned)a2 < (unsigned)CHUNK) acc[r] += sh[a2];
                if ((unsigned)a3 < (unsigned)CHUNK) acc[r] += sh[a3];
            }
        }
    }

    // reduce across lanes and store
    #pragma unroll
    for (int r = 0; r < 4; ++r) {
        float s = acc[r];
        #pragma unroll
        for (int off = 32; off > 0; off >>= 1)
            s += __shfl_xor(s, off, 64);
        if (lane == 0) out[row0 + r] = s * (1.0f / LL);
    }
}

extern "C" void kernel_launch(void* const* d_in, const int* in_sizes, int n_in,
                              void* d_out, int out_size, void* d_ws, size_t ws_size,
                              hipStream_t stream) {
    const int4*   idx4   = (const int4*)d_in[0];      // [B, L] int32 as int4
    const float4* E4     = (const float4*)d_in[1];    // [V, D] f32 as float4
    const float4* w4     = (const float4*)d_in[2];    // [D, 1] f32 as float4
    float*        out    = (float*)d_out;             // [B, 1] f32
    float*        rowdot = (float*)d_ws;              // 400 KB scratch
                                                      // (stage reads to 400,032 B; ws is far larger)

    // 100000 rows, 2 rows/wave, 4 waves/block -> 12500 blocks
    rowdot_kernel<<<VV / 8, 256, 0, stream>>>(E4, w4, rowdot);
    // 16384 rows / 64 rows per block -> 256 blocks of 1024 threads
    pool_kernel<<<BB / 64, 1024, 0, stream>>>(idx4, rowdot, out);
}